// Round 10
// baseline (295.417 us; speedup 1.0000x reference)
//
#include <hip/hip_runtime.h>
#include <math.h>

#define NF 256
#define NHEADS 8
#define MNEG -1e30f
#define INVLN2 1.4426950408889634f

typedef _Float16 half8 __attribute__((ext_vector_type(8)));
typedef float f32x4 __attribute__((ext_vector_type(4)));

// ---------------- CSR phase A: deg_count (blocks [0,nbE)) ∥ prep_w (blocks [nbE,nbE+512)) ----------------

__global__ __launch_bounds__(256) void misc_k(const int* __restrict__ edst, int* __restrict__ deg, int E, int nbE,
                                              const float* __restrict__ W1, const float* __restrict__ W2,
                                              _Float16* __restrict__ O1, _Float16* __restrict__ O2) {
    int bid = blockIdx.x;
    if (bid < nbE) {
        int i = (bid * 256 + threadIdx.x) * 4;
        if (i + 4 <= E) {
            int4 d = *(const int4*)&edst[i];
            atomicAdd(&deg[d.x], 1);
            atomicAdd(&deg[d.y], 1);
            atomicAdd(&deg[d.z], 1);
            atomicAdd(&deg[d.w], 1);
        } else {
            for (int e = i; e < E; ++e) atomicAdd(&deg[edst[e]], 1);
        }
    } else {
        int tid = (bid - nbE) * 256 + threadIdx.x;   // 0..131071
        const float* W = (tid < 65536) ? W1 : W2;
        _Float16* O = (tid < 65536) ? O1 : O2;
        int t = tid & 65535;
        int k = t >> 8, c = t & 255;
        O[(size_t)c * 256 + k] = (_Float16)W[t];
    }
}

__global__ __launch_bounds__(256) void scan1_k(const int* __restrict__ deg, int* __restrict__ indptr,
                                               int* __restrict__ bsum, int n) {
    __shared__ int sh[256];
    int tid = threadIdx.x;
    int i = blockIdx.x * 256 + tid;
    int d = (i < n) ? deg[i] : 0;
    sh[tid] = d;
    __syncthreads();
#pragma unroll
    for (int off = 1; off < 256; off <<= 1) {
        int t = (tid >= off) ? sh[tid - off] : 0;
        __syncthreads();
        sh[tid] += t;
        __syncthreads();
    }
    if (i < n) indptr[i] = sh[tid] - d;
    if (tid == 255) bsum[blockIdx.x] = sh[255];
}

// scan of block sums (redundant per block) + finalize indptr + seed self-loop/cursor
__global__ __launch_bounds__(256) void scan3_k(const int* __restrict__ deg, int* __restrict__ indptr,
                                               const int* __restrict__ bsum, int* __restrict__ cursor,
                                               int* __restrict__ srcs, int n, int nb) {
    __shared__ int sh[256];
    int tid = threadIdx.x;
    int d = (tid < nb) ? bsum[tid] : 0;
    sh[tid] = d;
    __syncthreads();
#pragma unroll
    for (int off = 1; off < 256; off <<= 1) {
        int t = (tid >= off) ? sh[tid - off] : 0;
        __syncthreads();
        sh[tid] += t;
        __syncthreads();
    }
    int bid = blockIdx.x;
    int boff = sh[bid] - ((bid < nb) ? bsum[bid] : 0);
    int i = bid * 256 + tid;
    if (i < n) {
        int v = indptr[i] + boff + i;
        indptr[i] = v;
        srcs[v] = i;           // self loop first
        cursor[i] = v + 1;
        if (i == n - 1) indptr[n] = v + deg[i] + 1;
    }
}

// ---------------- MFMA f16 GEMM + fused alpha (double-buffered, BK=32) ∥ fill_edge ----------------
// Blocks [0,GB): GEMM, 512 thr = 8 waves (2m x 4n), tile 128x256.
// Blocks [GB,...): fill_edge, 4 edges/thread. aS/aD written in exp2 domain (x 1/ln2).

template <int AF32>
__global__ __launch_bounds__(512, 4) void gemm_mfma_k(const void* __restrict__ Av, const _Float16* __restrict__ WTh,
                                                      const float* __restrict__ att_s, const float* __restrict__ att_d,
                                                      _Float16* __restrict__ C, float* __restrict__ aS,
                                                      float* __restrict__ aD, int M,
                                                      const int* __restrict__ esrc, const int* __restrict__ edst,
                                                      int* __restrict__ cursor, int* __restrict__ srcs,
                                                      int E, int GB) {
    __shared__ __align__(16) _Float16 Asub[2][128][40];
    __shared__ __align__(16) _Float16 Wsub[2][256][40];
    if (blockIdx.x >= GB) {   // fill_edge part
        int i = ((blockIdx.x - GB) * 512 + threadIdx.x) * 4;
        if (i + 4 <= E) {
            int4 s = *(const int4*)&esrc[i];
            int4 d = *(const int4*)&edst[i];
            srcs[atomicAdd(&cursor[d.x], 1)] = s.x;
            srcs[atomicAdd(&cursor[d.y], 1)] = s.y;
            srcs[atomicAdd(&cursor[d.z], 1)] = s.z;
            srcs[atomicAdd(&cursor[d.w], 1)] = s.w;
        } else {
            for (int e = i; e < E; ++e) srcs[atomicAdd(&cursor[edst[e]], 1)] = esrc[e];
        }
        return;
    }
    int t = threadIdx.x;
    int wave = t >> 6, lane = t & 63;
    int wm = wave >> 2, wn = wave & 3;        // 2 x 4 wave grid
    int lr = lane & 15, lg = lane >> 4;
    int r0 = blockIdx.x * 128;
    const float* Af = (const float*)Av;
    const _Float16* Ah = (const _Float16*)Av;

    int arow = t >> 2, aoff = (t & 3) * 8;      // 8 halfs
    int wcol = t >> 1, woff = (t & 1) * 16;     // 16 halfs
    int ga_row = r0 + arow; ga_row = ga_row < M ? ga_row : M - 1;

    half8 aR, wR0, wR1;
    {
        if (AF32) {
            const float* p = Af + (size_t)ga_row * 256 + aoff;
            float4 x0 = *(const float4*)p;
            float4 x1 = *(const float4*)(p + 4);
            aR[0] = (_Float16)x0.x; aR[1] = (_Float16)x0.y; aR[2] = (_Float16)x0.z; aR[3] = (_Float16)x0.w;
            aR[4] = (_Float16)x1.x; aR[5] = (_Float16)x1.y; aR[6] = (_Float16)x1.z; aR[7] = (_Float16)x1.w;
        } else {
            aR = *(const half8*)(Ah + (size_t)ga_row * 256 + aoff);
        }
        const _Float16* p = WTh + (size_t)wcol * 256 + woff;
        wR0 = *(const half8*)p;
        wR1 = *(const half8*)(p + 8);
    }
    *(half8*)&Asub[0][arow][aoff] = aR;
    *(half8*)&Wsub[0][wcol][woff] = wR0;
    *(half8*)&Wsub[0][wcol][woff + 8] = wR1;
    __syncthreads();

    f32x4 acc[4][4];
#pragma unroll
    for (int mr = 0; mr < 4; ++mr)
#pragma unroll
        for (int nr = 0; nr < 4; ++nr) acc[mr][nr] = (f32x4){0.f, 0.f, 0.f, 0.f};

#pragma unroll
    for (int ks = 0; ks < 8; ++ks) {
        int cur = ks & 1;
        if (ks < 7) {
            int k0 = (ks + 1) * 32;
            if (AF32) {
                const float* p = Af + (size_t)ga_row * 256 + k0 + aoff;
                float4 x0 = *(const float4*)p;
                float4 x1 = *(const float4*)(p + 4);
                aR[0] = (_Float16)x0.x; aR[1] = (_Float16)x0.y; aR[2] = (_Float16)x0.z; aR[3] = (_Float16)x0.w;
                aR[4] = (_Float16)x1.x; aR[5] = (_Float16)x1.y; aR[6] = (_Float16)x1.z; aR[7] = (_Float16)x1.w;
            } else {
                aR = *(const half8*)(Ah + (size_t)ga_row * 256 + k0 + aoff);
            }
            const _Float16* p = WTh + (size_t)wcol * 256 + k0 + woff;
            wR0 = *(const half8*)p;
            wR1 = *(const half8*)(p + 8);
        }
        {
            half8 a[4], b[4];
#pragma unroll
            for (int mr = 0; mr < 4; ++mr)
                a[mr] = *(const half8*)&Asub[cur][wm * 64 + mr * 16 + lr][lg * 8];
#pragma unroll
            for (int nr = 0; nr < 4; ++nr)
                b[nr] = *(const half8*)&Wsub[cur][wn * 64 + nr * 16 + lr][lg * 8];
#pragma unroll
            for (int mr = 0; mr < 4; ++mr)
#pragma unroll
                for (int nr = 0; nr < 4; ++nr)
                    acc[mr][nr] = __builtin_amdgcn_mfma_f32_16x16x32_f16(a[mr], b[nr], acc[mr][nr], 0, 0, 0);
        }
        if (ks < 7) {
            __syncthreads();
            *(half8*)&Asub[cur ^ 1][arow][aoff] = aR;
            *(half8*)&Wsub[cur ^ 1][wcol][woff] = wR0;
            *(half8*)&Wsub[cur ^ 1][wcol][woff + 8] = wR1;
            __syncthreads();
        }
    }

    int c0 = wn * 64;
    int h0 = wn * 2, h1 = wn * 2 + 1;
    // exp2-domain: scale attention coefficients by 1/ln2
    float as_c0 = att_s[h0 * 32 + lr] * INVLN2, as_c1 = att_s[h0 * 32 + 16 + lr] * INVLN2;
    float as_c2 = att_s[h1 * 32 + lr] * INVLN2, as_c3 = att_s[h1 * 32 + 16 + lr] * INVLN2;
    float ad_c0 = att_d[h0 * 32 + lr] * INVLN2, ad_c1 = att_d[h0 * 32 + 16 + lr] * INVLN2;
    float ad_c2 = att_d[h1 * 32 + lr] * INVLN2, ad_c3 = att_d[h1 * 32 + 16 + lr] * INVLN2;

#pragma unroll
    for (int mr = 0; mr < 4; ++mr) {
        int rbase = r0 + wm * 64 + mr * 16 + lg * 4;
#pragma unroll
        for (int j = 0; j < 4; ++j) {
            int row = rbase + j;
            float ps0 = acc[mr][0][j] * as_c0 + acc[mr][1][j] * as_c1;
            float ps1 = acc[mr][2][j] * as_c2 + acc[mr][3][j] * as_c3;
            float pd0 = acc[mr][0][j] * ad_c0 + acc[mr][1][j] * ad_c1;
            float pd1 = acc[mr][2][j] * ad_c2 + acc[mr][3][j] * ad_c3;
#pragma unroll
            for (int o = 1; o < 16; o <<= 1) {
                ps0 += __shfl_xor(ps0, o);
                ps1 += __shfl_xor(ps1, o);
                pd0 += __shfl_xor(pd0, o);
                pd1 += __shfl_xor(pd1, o);
            }
            if (row < M) {
#pragma unroll
                for (int nr = 0; nr < 4; ++nr)
                    C[(size_t)row * 256 + c0 + nr * 16 + lr] = (_Float16)acc[mr][nr][j];
                if (lr == 0) {
                    aS[(size_t)row * NHEADS + h0] = ps0;
                    aS[(size_t)row * NHEADS + h1] = ps1;
                    aD[(size_t)row * NHEADS + h0] = pd0;
                    aD[(size_t)row * NHEADS + h1] = pd1;
                }
            }
        }
    }
}

// ---------------- aggregation: wave per dst, 8 pairs (16 edges) per iter, exp2 softmax ----------------
// MODE 0: write fp16 row (layer1). MODE 1: fuse layer-3 matvec -> h3/s3/d3 (layer2).

template <int MODE>
__global__ __launch_bounds__(256) void agg_k(const _Float16* __restrict__ h, const float* __restrict__ aS,
                                             const float* __restrict__ aD, const int* __restrict__ indptr,
                                             const int* __restrict__ srcs, const float* __restrict__ bias,
                                             _Float16* __restrict__ out,
                                             const float* __restrict__ W3, const float* __restrict__ as3,
                                             const float* __restrict__ ad3, float* __restrict__ h3,
                                             float* __restrict__ s3, float* __restrict__ d3, int N) {
    int wid = blockIdx.x * 4 + (threadIdx.x >> 6);
    if (wid >= N) return;
    int lane = threadIdx.x & 63;
    int hf = lane >> 5;          // which edge of a pair
    int cl = lane & 31;          // channel-lane: 8 ch at cl*8
    int hh = cl >> 2;            // head
    float ad = aD[(size_t)wid * NHEADS + hh];
    int beg = indptr[wid], end = indptr[wid + 1];
    const half8* h8p = (const half8*)h;
    float m = MNEG, den = 0.f;
    float f0 = 0, f1 = 0, f2 = 0, f3 = 0, f4 = 0, f5 = 0, f6 = 0, f7 = 0;
    int k = beg;
    int sp[8]; float asp[8];
    if (k + 16 <= end) {
#pragma unroll
        for (int j = 0; j < 8; ++j) sp[j] = srcs[k + 2 * j + hf];
#pragma unroll
        for (int j = 0; j < 8; ++j) asp[j] = aS[(size_t)sp[j] * NHEADS + hh];
    }
    for (; k + 16 <= end; k += 16) {
        int s[8]; float as[8]; half8 v[8]; float e[8];
#pragma unroll
        for (int j = 0; j < 8; ++j) { s[j] = sp[j]; as[j] = asp[j]; }
        // issue all 8 row-gathers first (8 KB in flight per wave)
#pragma unroll
        for (int j = 0; j < 8; ++j) v[j] = h8p[(size_t)s[j] * 32 + cl];
        if (k + 32 <= end) {   // prefetch next iteration
#pragma unroll
            for (int j = 0; j < 8; ++j) sp[j] = srcs[k + 16 + 2 * j + hf];
#pragma unroll
            for (int j = 0; j < 8; ++j) asp[j] = aS[(size_t)sp[j] * NHEADS + hh];
        }
#pragma unroll
        for (int j = 0; j < 8; ++j) { e[j] = as[j] + ad; e[j] = fmaxf(e[j], 0.2f * e[j]); }
        float em = fmaxf(fmaxf(fmaxf(e[0], e[1]), fmaxf(e[2], e[3])),
                         fmaxf(fmaxf(e[4], e[5]), fmaxf(e[6], e[7])));
        if (__any(em > m + 4.f)) {
            float mn = fmaxf(m, em);
            float sc = exp2f(m - mn);
            den *= sc; f0 *= sc; f1 *= sc; f2 *= sc; f3 *= sc; f4 *= sc; f5 *= sc; f6 *= sc; f7 *= sc;
            m = mn;
        }
        half8 hacc = (half8)(_Float16)0.f;   // p <= 2^4=16, 8 terms: |sum| < 1k << 65504
#pragma unroll
        for (int j = 0; j < 8; ++j) {
            float p = exp2f(e[j] - m);
            den += p;
            _Float16 ph = (_Float16)p;
            half8 pb = {ph, ph, ph, ph, ph, ph, ph, ph};
            hacc += v[j] * pb;
        }
        f0 += (float)hacc[0]; f1 += (float)hacc[1]; f2 += (float)hacc[2]; f3 += (float)hacc[3];
        f4 += (float)hacc[4]; f5 += (float)hacc[5]; f6 += (float)hacc[6]; f7 += (float)hacc[7];
    }
    for (; k + 4 <= end; k += 4) {   // 2-pair mid loop
        int s0 = srcs[k + hf], s1 = srcs[k + 2 + hf];
        float a0 = aS[(size_t)s0 * NHEADS + hh], a1 = aS[(size_t)s1 * NHEADS + hh];
        half8 v0 = h8p[(size_t)s0 * 32 + cl], v1 = h8p[(size_t)s1 * 32 + cl];
        float e0 = a0 + ad; e0 = fmaxf(e0, 0.2f * e0);
        float e1 = a1 + ad; e1 = fmaxf(e1, 0.2f * e1);
        float em = fmaxf(e0, e1);
        if (__any(em > m + 4.f)) {
            float mn = fmaxf(m, em);
            float sc = exp2f(m - mn);
            den *= sc; f0 *= sc; f1 *= sc; f2 *= sc; f3 *= sc; f4 *= sc; f5 *= sc; f6 *= sc; f7 *= sc;
            m = mn;
        }
        float p0 = exp2f(e0 - m), p1 = exp2f(e1 - m);
        den += p0 + p1;
        f0 += p0 * (float)v0[0] + p1 * (float)v1[0];
        f1 += p0 * (float)v0[1] + p1 * (float)v1[1];
        f2 += p0 * (float)v0[2] + p1 * (float)v1[2];
        f3 += p0 * (float)v0[3] + p1 * (float)v1[3];
        f4 += p0 * (float)v0[4] + p1 * (float)v1[4];
        f5 += p0 * (float)v0[5] + p1 * (float)v1[5];
        f6 += p0 * (float)v0[6] + p1 * (float)v1[6];
        f7 += p0 * (float)v0[7] + p1 * (float)v1[7];
    }
    for (; k + 2 <= end; k += 2) {
        int s = srcs[k + hf];
        float as = aS[(size_t)s * NHEADS + hh];
        half8 v = h8p[(size_t)s * 32 + cl];
        float e = as + ad; e = fmaxf(e, 0.2f * e);
        if (__any(e > m + 4.f)) {
            float mn = fmaxf(m, e);
            float sc = exp2f(m - mn);
            den *= sc; f0 *= sc; f1 *= sc; f2 *= sc; f3 *= sc; f4 *= sc; f5 *= sc; f6 *= sc; f7 *= sc;
            m = mn;
        }
        float p = exp2f(e - m);
        den += p;
        f0 += p * (float)v[0]; f1 += p * (float)v[1]; f2 += p * (float)v[2]; f3 += p * (float)v[3];
        f4 += p * (float)v[4]; f5 += p * (float)v[5]; f6 += p * (float)v[6]; f7 += p * (float)v[7];
    }
    if (k < end) {   // odd tail: lanes hf==0 only
        int s = srcs[k];
        float e = aS[(size_t)s * NHEADS + hh] + ad;
        e = fmaxf(e, 0.2f * e);
        half8 v = h8p[(size_t)s * 32 + cl];
        float eg = (hf == 0) ? e : MNEG;
        if (__any(eg > m + 4.f)) {
            float mn = fmaxf(m, eg);
            float sc = exp2f(m - mn);
            den *= sc; f0 *= sc; f1 *= sc; f2 *= sc; f3 *= sc; f4 *= sc; f5 *= sc; f6 *= sc; f7 *= sc;
            m = mn;
        }
        float p = (hf == 0) ? exp2f(e - m) : 0.f;
        den += p;
        f0 += p * (float)v[0]; f1 += p * (float)v[1]; f2 += p * (float)v[2]; f3 += p * (float)v[3];
        f4 += p * (float)v[4]; f5 += p * (float)v[5]; f6 += p * (float)v[6]; f7 += p * (float)v[7];
    }
    // merge the two half-states (lane l <-> l+32)
    {
        float m2 = __shfl_xor(m, 32);
        float den2 = __shfl_xor(den, 32);
        float mn = fmaxf(m, m2);
        float sc1 = exp2f(m - mn), sc2 = exp2f(m2 - mn);
        den = den * sc1 + den2 * sc2;
        f0 = f0 * sc1 + __shfl_xor(f0, 32) * sc2;
        f1 = f1 * sc1 + __shfl_xor(f1, 32) * sc2;
        f2 = f2 * sc1 + __shfl_xor(f2, 32) * sc2;
        f3 = f3 * sc1 + __shfl_xor(f3, 32) * sc2;
        f4 = f4 * sc1 + __shfl_xor(f4, 32) * sc2;
        f5 = f5 * sc1 + __shfl_xor(f5, 32) * sc2;
        f6 = f6 * sc1 + __shfl_xor(f6, 32) * sc2;
        f7 = f7 * sc1 + __shfl_xor(f7, 32) * sc2;
    }
    float inv = 1.f / (den + 1e-16f);
    float4 bv0 = *(const float4*)&bias[cl * 8];
    float4 bv1 = *(const float4*)&bias[cl * 8 + 4];
    float o[8];
    o[0] = f0 * inv + bv0.x; o[1] = f1 * inv + bv0.y; o[2] = f2 * inv + bv0.z; o[3] = f3 * inv + bv0.w;
    o[4] = f4 * inv + bv1.x; o[5] = f5 * inv + bv1.y; o[6] = f6 * inv + bv1.z; o[7] = f7 * inv + bv1.w;
#pragma unroll
    for (int c = 0; c < 8; ++c) o[c] = (o[c] > 0.f) ? o[c] : expm1f(o[c]);  // ELU

    if (MODE == 0) {
        if (hf == 0) {
            half8 ov;
#pragma unroll
            for (int c = 0; c < 8; ++c) ov[c] = (_Float16)o[c];
            ((half8*)out)[(size_t)wid * 32 + cl] = ov;
        }
    } else {
        const float4* W34 = (const float4*)W3;
        float p0 = 0.f, p1 = 0.f;
#pragma unroll
        for (int q = 0; q < 4; ++q) {
            float4 w = W34[cl * 4 + q];
            p0 += o[2 * q] * w.x + o[2 * q + 1] * w.z;
            p1 += o[2 * q] * w.y + o[2 * q + 1] * w.w;
        }
#pragma unroll
        for (int off = 1; off < 32; off <<= 1) {
            p0 += __shfl_xor(p0, off);
            p1 += __shfl_xor(p1, off);
        }
        if (lane == 0) {
            h3[(size_t)wid * 2] = p0;
            h3[(size_t)wid * 2 + 1] = p1;
            // exp2 domain for layer-3 logits
            s3[wid] = (p0 * as3[0] + p1 * as3[1]) * INVLN2;
            d3[wid] = (p0 * ad3[0] + p1 * ad3[1]) * INVLN2;
        }
    }
}

// ---------------- layer 3 aggregation: 4 lanes per dst node + shuffle merge (exp2 domain) ----------------

__global__ __launch_bounds__(256) void agg3_k(const float* __restrict__ h3, const float* __restrict__ s3,
                                              const float* __restrict__ d3, const int* __restrict__ indptr,
                                              const int* __restrict__ srcs, const float* __restrict__ b3,
                                              float* __restrict__ out, int N) {
    int t = blockIdx.x * 256 + threadIdx.x;
    int n = t >> 2;
    if (n >= N) return;
    int sub = t & 3;
    float ad = d3[n];
    float m = MNEG, den = 0.f, a0 = 0.f, a1 = 0.f;
    int beg = indptr[n], end = indptr[n + 1];
    for (int k = beg + sub; k < end; k += 4) {
        int s = srcs[k];
        float e = s3[s] + ad;
        e = fmaxf(e, 0.2f * e);
        if (e > m + 4.f) {
            float mn = fmaxf(m, e);
            float sc = exp2f(m - mn);
            den *= sc; a0 *= sc; a1 *= sc;
            m = mn;
        }
        float p = exp2f(e - m);
        den += p;
        a0 += p * h3[(size_t)s * 2];
        a1 += p * h3[(size_t)s * 2 + 1];
    }
#pragma unroll
    for (int off = 1; off < 4; off <<= 1) {
        float m2 = __shfl_xor(m, off);
        float den2 = __shfl_xor(den, off);
        float a02 = __shfl_xor(a0, off);
        float a12 = __shfl_xor(a1, off);
        float mn = fmaxf(m, m2);
        float sc1 = exp2f(m - mn);
        float sc2 = exp2f(m2 - mn);
        den = den * sc1 + den2 * sc2;
        a0 = a0 * sc1 + a02 * sc2;
        a1 = a1 * sc1 + a12 * sc2;
        m = mn;
    }
    if (sub == 0) {
        float inv = 1.f / (den + 1e-16f);
        out[(size_t)n * 2]     = a0 * inv + b3[0];
        out[(size_t)n * 2 + 1] = a1 * inv + b3[1];
    }
}

// ---------------- launch ----------------

extern "C" void kernel_launch(void* const* d_in, const int* in_sizes, int n_in,
                              void* d_out, int out_size, void* d_ws, size_t ws_size,
                              hipStream_t stream) {
    const float* x   = (const float*)d_in[0];
    const int*   ei  = (const int*)d_in[1];
    const float* W1  = (const float*)d_in[2];
    const float* as1 = (const float*)d_in[3];
    const float* ad1 = (const float*)d_in[4];
    const float* b1  = (const float*)d_in[5];
    const float* W2  = (const float*)d_in[6];
    const float* as2 = (const float*)d_in[7];
    const float* ad2 = (const float*)d_in[8];
    const float* b2  = (const float*)d_in[9];
    const float* W3  = (const float*)d_in[10];
    const float* at_s3 = (const float*)d_in[11];
    const float* at_d3 = (const float*)d_in[12];
    const float* b3  = (const float*)d_in[13];

    int N = in_sizes[0] / NF;   // 50000
    int E = in_sizes[1] / 2;    // 800000
    const int* esrc = ei;
    const int* edst = ei + E;

    char* w = (char*)d_ws;
    _Float16* hbuf  = (_Float16*)w; w += (size_t)N * NF * 2;
    _Float16* xnext = (_Float16*)w; w += (size_t)N * NF * 2;
    float* aS    = (float*)w; w += (size_t)N * NHEADS * 4;
    float* aD    = (float*)w; w += (size_t)N * NHEADS * 4;
    float* h3    = (float*)w; w += (size_t)N * 2 * 4;
    float* s3    = (float*)w; w += (size_t)N * 4;
    float* d3    = (float*)w; w += (size_t)N * 4;
    int* deg     = (int*)w; w += (size_t)N * 4;
    int* indptr  = (int*)w; w += (size_t)(N + 1) * 4 + 60;
    int* cursor  = (int*)w; w += (size_t)N * 4;
    int* bsum    = (int*)w; w += 256 * 4;
    _Float16* WTh1 = (_Float16*)w; w += (size_t)256 * 256 * 2;
    _Float16* WTh2 = (_Float16*)w; w += (size_t)256 * 256 * 2;
    int* srcs    = (int*)w;

    int nb_n = (N + 255) / 256;       // 196
    int nb_e4 = (E + 1023) / 1024;    // 782 (deg_count blocks)
    int nb_f  = (E + 2047) / 2048;    // 391 (fill blocks, 512 thr x 4 edges)
    int nb_w = (N + 3) / 4;
    int nb_gm = (N + 127) / 128;      // 391
    int nb_a3 = (N * 4 + 255) / 256;

    // CSR build overlapped with weight prep / GEMM1
    hipMemsetAsync(deg, 0, (size_t)N * 4, stream);
    misc_k<<<nb_e4 + 512, 256, 0, stream>>>(edst, deg, E, nb_e4, W1, W2, WTh1, WTh2);
    scan1_k<<<nb_n, 256, 0, stream>>>(deg, indptr, bsum, N);
    scan3_k<<<nb_n, 256, 0, stream>>>(deg, indptr, bsum, cursor, srcs, N, nb_n);

    // layer 1 GEMM ∥ fill_edge
    gemm_mfma_k<1><<<nb_gm + nb_f, 512, 0, stream>>>(x, WTh1, as1, ad1, hbuf, aS, aD, N,
                                                     esrc, edst, cursor, srcs, E, nb_gm);
    agg_k<0><<<nb_w, 256, 0, stream>>>(hbuf, aS, aD, indptr, srcs, b1, xnext,
                                       nullptr, nullptr, nullptr, nullptr, nullptr, nullptr, N);
    // layer 2 (+ fused layer-3 matvec)
    gemm_mfma_k<0><<<nb_gm, 512, 0, stream>>>(xnext, WTh2, as2, ad2, hbuf, aS, aD, N,
                                              nullptr, nullptr, nullptr, nullptr, 0, nb_gm);
    agg_k<1><<<nb_w, 256, 0, stream>>>(hbuf, aS, aD, indptr, srcs, b2, nullptr,
                                       W3, at_s3, at_d3, h3, s3, d3, N);
    // layer 3 aggregation
    agg3_k<<<nb_a3, 256, 0, stream>>>(h3, s3, d3, indptr, srcs, b3, (float*)d_out, N);
}

// Round 11
// 275.707 us; speedup vs baseline: 1.0715x; 1.0715x over previous
//
#include <hip/hip_runtime.h>
#include <math.h>

#define NF 256
#define NHEADS 8
#define MNEG -1e30f
#define INVLN2 1.4426950408889634f

typedef _Float16 half8 __attribute__((ext_vector_type(8)));
typedef float f32x4 __attribute__((ext_vector_type(4)));

// ---------------- CSR phase A: deg_count (blocks [0,nbE)) ∥ prep_w (blocks [nbE,nbE+512)) ----------------

__global__ __launch_bounds__(256) void misc_k(const int* __restrict__ edst, int* __restrict__ deg, int E, int nbE,
                                              const float* __restrict__ W1, const float* __restrict__ W2,
                                              _Float16* __restrict__ O1, _Float16* __restrict__ O2) {
    int bid = blockIdx.x;
    if (bid < nbE) {
        int i = (bid * 256 + threadIdx.x) * 4;
        if (i + 4 <= E) {
            int4 d = *(const int4*)&edst[i];
            atomicAdd(&deg[d.x], 1);
            atomicAdd(&deg[d.y], 1);
            atomicAdd(&deg[d.z], 1);
            atomicAdd(&deg[d.w], 1);
        } else {
            for (int e = i; e < E; ++e) atomicAdd(&deg[edst[e]], 1);
        }
    } else {
        int tid = (bid - nbE) * 256 + threadIdx.x;   // 0..131071
        const float* W = (tid < 65536) ? W1 : W2;
        _Float16* O = (tid < 65536) ? O1 : O2;
        int t = tid & 65535;
        int k = t >> 8, c = t & 255;
        O[(size_t)c * 256 + k] = (_Float16)W[t];
    }
}

__global__ __launch_bounds__(256) void scan1_k(const int* __restrict__ deg, int* __restrict__ indptr,
                                               int* __restrict__ bsum, int n) {
    __shared__ int sh[256];
    int tid = threadIdx.x;
    int i = blockIdx.x * 256 + tid;
    int d = (i < n) ? deg[i] : 0;
    sh[tid] = d;
    __syncthreads();
#pragma unroll
    for (int off = 1; off < 256; off <<= 1) {
        int t = (tid >= off) ? sh[tid - off] : 0;
        __syncthreads();
        sh[tid] += t;
        __syncthreads();
    }
    if (i < n) indptr[i] = sh[tid] - d;
    if (tid == 255) bsum[blockIdx.x] = sh[255];
}

// scan of block sums (redundant per block) + finalize indptr + seed self-loop/cursor
__global__ __launch_bounds__(256) void scan3_k(const int* __restrict__ deg, int* __restrict__ indptr,
                                               const int* __restrict__ bsum, int* __restrict__ cursor,
                                               int* __restrict__ srcs, int n, int nb) {
    __shared__ int sh[256];
    int tid = threadIdx.x;
    int d = (tid < nb) ? bsum[tid] : 0;
    sh[tid] = d;
    __syncthreads();
#pragma unroll
    for (int off = 1; off < 256; off <<= 1) {
        int t = (tid >= off) ? sh[tid - off] : 0;
        __syncthreads();
        sh[tid] += t;
        __syncthreads();
    }
    int bid = blockIdx.x;
    int boff = sh[bid] - ((bid < nb) ? bsum[bid] : 0);
    int i = bid * 256 + tid;
    if (i < n) {
        int v = indptr[i] + boff + i;
        indptr[i] = v;
        srcs[v] = i;           // self loop first
        cursor[i] = v + 1;
        if (i == n - 1) indptr[n] = v + deg[i] + 1;
    }
}

// ---------------- MFMA f16 GEMM + fused alpha (double-buffered, BK=32) ∥ fill_edge ----------------
// Blocks [0,GB): GEMM, 512 thr = 8 waves (2m x 4n), tile 128x256.
// Blocks [GB,...): fill_edge, 4 edges/thread. aS/aD written in exp2 domain (x 1/ln2).

template <int AF32>
__global__ __launch_bounds__(512, 4) void gemm_mfma_k(const void* __restrict__ Av, const _Float16* __restrict__ WTh,
                                                      const float* __restrict__ att_s, const float* __restrict__ att_d,
                                                      _Float16* __restrict__ C, float* __restrict__ aS,
                                                      float* __restrict__ aD, int M,
                                                      const int* __restrict__ esrc, const int* __restrict__ edst,
                                                      int* __restrict__ cursor, int* __restrict__ srcs,
                                                      int E, int GB) {
    __shared__ __align__(16) _Float16 Asub[2][128][40];
    __shared__ __align__(16) _Float16 Wsub[2][256][40];
    if (blockIdx.x >= GB) {   // fill_edge part
        int i = ((blockIdx.x - GB) * 512 + threadIdx.x) * 4;
        if (i + 4 <= E) {
            int4 s = *(const int4*)&esrc[i];
            int4 d = *(const int4*)&edst[i];
            srcs[atomicAdd(&cursor[d.x], 1)] = s.x;
            srcs[atomicAdd(&cursor[d.y], 1)] = s.y;
            srcs[atomicAdd(&cursor[d.z], 1)] = s.z;
            srcs[atomicAdd(&cursor[d.w], 1)] = s.w;
        } else {
            for (int e = i; e < E; ++e) srcs[atomicAdd(&cursor[edst[e]], 1)] = esrc[e];
        }
        return;
    }
    int t = threadIdx.x;
    int wave = t >> 6, lane = t & 63;
    int wm = wave >> 2, wn = wave & 3;        // 2 x 4 wave grid
    int lr = lane & 15, lg = lane >> 4;
    int r0 = blockIdx.x * 128;
    const float* Af = (const float*)Av;
    const _Float16* Ah = (const _Float16*)Av;

    int arow = t >> 2, aoff = (t & 3) * 8;      // 8 halfs
    int wcol = t >> 1, woff = (t & 1) * 16;     // 16 halfs
    int ga_row = r0 + arow; ga_row = ga_row < M ? ga_row : M - 1;

    half8 aR, wR0, wR1;
    {
        if (AF32) {
            const float* p = Af + (size_t)ga_row * 256 + aoff;
            float4 x0 = *(const float4*)p;
            float4 x1 = *(const float4*)(p + 4);
            aR[0] = (_Float16)x0.x; aR[1] = (_Float16)x0.y; aR[2] = (_Float16)x0.z; aR[3] = (_Float16)x0.w;
            aR[4] = (_Float16)x1.x; aR[5] = (_Float16)x1.y; aR[6] = (_Float16)x1.z; aR[7] = (_Float16)x1.w;
        } else {
            aR = *(const half8*)(Ah + (size_t)ga_row * 256 + aoff);
        }
        const _Float16* p = WTh + (size_t)wcol * 256 + woff;
        wR0 = *(const half8*)p;
        wR1 = *(const half8*)(p + 8);
    }
    *(half8*)&Asub[0][arow][aoff] = aR;
    *(half8*)&Wsub[0][wcol][woff] = wR0;
    *(half8*)&Wsub[0][wcol][woff + 8] = wR1;
    __syncthreads();

    f32x4 acc[4][4];
#pragma unroll
    for (int mr = 0; mr < 4; ++mr)
#pragma unroll
        for (int nr = 0; nr < 4; ++nr) acc[mr][nr] = (f32x4){0.f, 0.f, 0.f, 0.f};

#pragma unroll
    for (int ks = 0; ks < 8; ++ks) {
        int cur = ks & 1;
        if (ks < 7) {
            int k0 = (ks + 1) * 32;
            if (AF32) {
                const float* p = Af + (size_t)ga_row * 256 + k0 + aoff;
                float4 x0 = *(const float4*)p;
                float4 x1 = *(const float4*)(p + 4);
                aR[0] = (_Float16)x0.x; aR[1] = (_Float16)x0.y; aR[2] = (_Float16)x0.z; aR[3] = (_Float16)x0.w;
                aR[4] = (_Float16)x1.x; aR[5] = (_Float16)x1.y; aR[6] = (_Float16)x1.z; aR[7] = (_Float16)x1.w;
            } else {
                aR = *(const half8*)(Ah + (size_t)ga_row * 256 + k0 + aoff);
            }
            const _Float16* p = WTh + (size_t)wcol * 256 + k0 + woff;
            wR0 = *(const half8*)p;
            wR1 = *(const half8*)(p + 8);
        }
        {
            half8 a[4], b[4];
#pragma unroll
            for (int mr = 0; mr < 4; ++mr)
                a[mr] = *(const half8*)&Asub[cur][wm * 64 + mr * 16 + lr][lg * 8];
#pragma unroll
            for (int nr = 0; nr < 4; ++nr)
                b[nr] = *(const half8*)&Wsub[cur][wn * 64 + nr * 16 + lr][lg * 8];
#pragma unroll
            for (int mr = 0; mr < 4; ++mr)
#pragma unroll
                for (int nr = 0; nr < 4; ++nr)
                    acc[mr][nr] = __builtin_amdgcn_mfma_f32_16x16x32_f16(a[mr], b[nr], acc[mr][nr], 0, 0, 0);
        }
        if (ks < 7) {
            __syncthreads();
            *(half8*)&Asub[cur ^ 1][arow][aoff] = aR;
            *(half8*)&Wsub[cur ^ 1][wcol][woff] = wR0;
            *(half8*)&Wsub[cur ^ 1][wcol][woff + 8] = wR1;
            __syncthreads();
        }
    }

    int c0 = wn * 64;
    int h0 = wn * 2, h1 = wn * 2 + 1;
    // exp2-domain: scale attention coefficients by 1/ln2
    float as_c0 = att_s[h0 * 32 + lr] * INVLN2, as_c1 = att_s[h0 * 32 + 16 + lr] * INVLN2;
    float as_c2 = att_s[h1 * 32 + lr] * INVLN2, as_c3 = att_s[h1 * 32 + 16 + lr] * INVLN2;
    float ad_c0 = att_d[h0 * 32 + lr] * INVLN2, ad_c1 = att_d[h0 * 32 + 16 + lr] * INVLN2;
    float ad_c2 = att_d[h1 * 32 + lr] * INVLN2, ad_c3 = att_d[h1 * 32 + 16 + lr] * INVLN2;

#pragma unroll
    for (int mr = 0; mr < 4; ++mr) {
        int rbase = r0 + wm * 64 + mr * 16 + lg * 4;
#pragma unroll
        for (int j = 0; j < 4; ++j) {
            int row = rbase + j;
            float ps0 = acc[mr][0][j] * as_c0 + acc[mr][1][j] * as_c1;
            float ps1 = acc[mr][2][j] * as_c2 + acc[mr][3][j] * as_c3;
            float pd0 = acc[mr][0][j] * ad_c0 + acc[mr][1][j] * ad_c1;
            float pd1 = acc[mr][2][j] * ad_c2 + acc[mr][3][j] * ad_c3;
#pragma unroll
            for (int o = 1; o < 16; o <<= 1) {
                ps0 += __shfl_xor(ps0, o);
                ps1 += __shfl_xor(ps1, o);
                pd0 += __shfl_xor(pd0, o);
                pd1 += __shfl_xor(pd1, o);
            }
            if (row < M) {
#pragma unroll
                for (int nr = 0; nr < 4; ++nr)
                    C[(size_t)row * 256 + c0 + nr * 16 + lr] = (_Float16)acc[mr][nr][j];
                if (lr == 0) {
                    aS[(size_t)row * NHEADS + h0] = ps0;
                    aS[(size_t)row * NHEADS + h1] = ps1;
                    aD[(size_t)row * NHEADS + h0] = pd0;
                    aD[(size_t)row * NHEADS + h1] = pd1;
                }
            }
        }
    }
}

// ---------------- aggregation: wave per dst, 4 pairs (8 edges) per iter, exp2 softmax ----------------
// MODE 0: write fp16 row (layer1). MODE 1: fuse layer-3 matvec -> h3/s3/d3 (layer2).

template <int MODE>
__global__ __launch_bounds__(256) void agg_k(const _Float16* __restrict__ h, const float* __restrict__ aS,
                                             const float* __restrict__ aD, const int* __restrict__ indptr,
                                             const int* __restrict__ srcs, const float* __restrict__ bias,
                                             _Float16* __restrict__ out,
                                             const float* __restrict__ W3, const float* __restrict__ as3,
                                             const float* __restrict__ ad3, float* __restrict__ h3,
                                             float* __restrict__ s3, float* __restrict__ d3, int N) {
    int wid = blockIdx.x * 4 + (threadIdx.x >> 6);
    if (wid >= N) return;
    int lane = threadIdx.x & 63;
    int hf = lane >> 5;          // which edge of a pair
    int cl = lane & 31;          // channel-lane: 8 ch at cl*8
    int hh = cl >> 2;            // head
    float ad = aD[(size_t)wid * NHEADS + hh];
    int beg = indptr[wid], end = indptr[wid + 1];
    const half8* h8p = (const half8*)h;
    float m = MNEG, den = 0.f;
    float f0 = 0, f1 = 0, f2 = 0, f3 = 0, f4 = 0, f5 = 0, f6 = 0, f7 = 0;
    int k = beg;
    int sp[4]; float asp[4];
    if (k + 8 <= end) {
#pragma unroll
        for (int j = 0; j < 4; ++j) sp[j] = srcs[k + 2 * j + hf];
#pragma unroll
        for (int j = 0; j < 4; ++j) asp[j] = aS[(size_t)sp[j] * NHEADS + hh];
    }
    for (; k + 8 <= end; k += 8) {
        int s[4]; float as[4]; half8 v[4]; float e[4];
#pragma unroll
        for (int j = 0; j < 4; ++j) { s[j] = sp[j]; as[j] = asp[j]; }
        // issue 4 row-gathers
#pragma unroll
        for (int j = 0; j < 4; ++j) v[j] = h8p[(size_t)s[j] * 32 + cl];
        if (k + 16 <= end) {   // prefetch next iteration's srcs+aS
#pragma unroll
            for (int j = 0; j < 4; ++j) sp[j] = srcs[k + 8 + 2 * j + hf];
#pragma unroll
            for (int j = 0; j < 4; ++j) asp[j] = aS[(size_t)sp[j] * NHEADS + hh];
        }
#pragma unroll
        for (int j = 0; j < 4; ++j) { e[j] = as[j] + ad; e[j] = fmaxf(e[j], 0.2f * e[j]); }
        float em = fmaxf(fmaxf(e[0], e[1]), fmaxf(e[2], e[3]));
        if (__any(em > m + 4.f)) {
            float mn = fmaxf(m, em);
            float sc = exp2f(m - mn);
            den *= sc; f0 *= sc; f1 *= sc; f2 *= sc; f3 *= sc; f4 *= sc; f5 *= sc; f6 *= sc; f7 *= sc;
            m = mn;
        }
        half8 hacc = (half8)(_Float16)0.f;   // p <= 2^4=16, 4 terms: bounded << 65504
#pragma unroll
        for (int j = 0; j < 4; ++j) {
            float p = exp2f(e[j] - m);
            den += p;
            _Float16 ph = (_Float16)p;
            half8 pb = {ph, ph, ph, ph, ph, ph, ph, ph};
            hacc += v[j] * pb;
        }
        f0 += (float)hacc[0]; f1 += (float)hacc[1]; f2 += (float)hacc[2]; f3 += (float)hacc[3];
        f4 += (float)hacc[4]; f5 += (float)hacc[5]; f6 += (float)hacc[6]; f7 += (float)hacc[7];
    }
    for (; k + 2 <= end; k += 2) {
        int s = srcs[k + hf];
        float as = aS[(size_t)s * NHEADS + hh];
        half8 v = h8p[(size_t)s * 32 + cl];
        float e = as + ad; e = fmaxf(e, 0.2f * e);
        if (__any(e > m + 4.f)) {
            float mn = fmaxf(m, e);
            float sc = exp2f(m - mn);
            den *= sc; f0 *= sc; f1 *= sc; f2 *= sc; f3 *= sc; f4 *= sc; f5 *= sc; f6 *= sc; f7 *= sc;
            m = mn;
        }
        float p = exp2f(e - m);
        den += p;
        f0 += p * (float)v[0]; f1 += p * (float)v[1]; f2 += p * (float)v[2]; f3 += p * (float)v[3];
        f4 += p * (float)v[4]; f5 += p * (float)v[5]; f6 += p * (float)v[6]; f7 += p * (float)v[7];
    }
    if (k < end) {   // odd tail: lanes hf==0 only
        int s = srcs[k];
        float e = aS[(size_t)s * NHEADS + hh] + ad;
        e = fmaxf(e, 0.2f * e);
        half8 v = h8p[(size_t)s * 32 + cl];
        float eg = (hf == 0) ? e : MNEG;
        if (__any(eg > m + 4.f)) {
            float mn = fmaxf(m, eg);
            float sc = exp2f(m - mn);
            den *= sc; f0 *= sc; f1 *= sc; f2 *= sc; f3 *= sc; f4 *= sc; f5 *= sc; f6 *= sc; f7 *= sc;
            m = mn;
        }
        float p = (hf == 0) ? exp2f(e - m) : 0.f;
        den += p;
        f0 += p * (float)v[0]; f1 += p * (float)v[1]; f2 += p * (float)v[2]; f3 += p * (float)v[3];
        f4 += p * (float)v[4]; f5 += p * (float)v[5]; f6 += p * (float)v[6]; f7 += p * (float)v[7];
    }
    // merge the two half-states (lane l <-> l+32)
    {
        float m2 = __shfl_xor(m, 32);
        float den2 = __shfl_xor(den, 32);
        float mn = fmaxf(m, m2);
        float sc1 = exp2f(m - mn), sc2 = exp2f(m2 - mn);
        den = den * sc1 + den2 * sc2;
        f0 = f0 * sc1 + __shfl_xor(f0, 32) * sc2;
        f1 = f1 * sc1 + __shfl_xor(f1, 32) * sc2;
        f2 = f2 * sc1 + __shfl_xor(f2, 32) * sc2;
        f3 = f3 * sc1 + __shfl_xor(f3, 32) * sc2;
        f4 = f4 * sc1 + __shfl_xor(f4, 32) * sc2;
        f5 = f5 * sc1 + __shfl_xor(f5, 32) * sc2;
        f6 = f6 * sc1 + __shfl_xor(f6, 32) * sc2;
        f7 = f7 * sc1 + __shfl_xor(f7, 32) * sc2;
    }
    float inv = 1.f / (den + 1e-16f);
    float4 bv0 = *(const float4*)&bias[cl * 8];
    float4 bv1 = *(const float4*)&bias[cl * 8 + 4];
    float o[8];
    o[0] = f0 * inv + bv0.x; o[1] = f1 * inv + bv0.y; o[2] = f2 * inv + bv0.z; o[3] = f3 * inv + bv0.w;
    o[4] = f4 * inv + bv1.x; o[5] = f5 * inv + bv1.y; o[6] = f6 * inv + bv1.z; o[7] = f7 * inv + bv1.w;
#pragma unroll
    for (int c = 0; c < 8; ++c) o[c] = (o[c] > 0.f) ? o[c] : expm1f(o[c]);  // ELU

    if (MODE == 0) {
        if (hf == 0) {
            half8 ov;
#pragma unroll
            for (int c = 0; c < 8; ++c) ov[c] = (_Float16)o[c];
            ((half8*)out)[(size_t)wid * 32 + cl] = ov;
        }
    } else {
        const float4* W34 = (const float4*)W3;
        float p0 = 0.f, p1 = 0.f;
#pragma unroll
        for (int q = 0; q < 4; ++q) {
            float4 w = W34[cl * 4 + q];
            p0 += o[2 * q] * w.x + o[2 * q + 1] * w.z;
            p1 += o[2 * q] * w.y + o[2 * q + 1] * w.w;
        }
#pragma unroll
        for (int off = 1; off < 32; off <<= 1) {
            p0 += __shfl_xor(p0, off);
            p1 += __shfl_xor(p1, off);
        }
        if (lane == 0) {
            h3[(size_t)wid * 2] = p0;
            h3[(size_t)wid * 2 + 1] = p1;
            // exp2 domain for layer-3 logits
            s3[wid] = (p0 * as3[0] + p1 * as3[1]) * INVLN2;
            d3[wid] = (p0 * ad3[0] + p1 * ad3[1]) * INVLN2;
        }
    }
}

// ---------------- layer 3 aggregation: 4 lanes per dst node + shuffle merge (exp2 domain) ----------------

__global__ __launch_bounds__(256) void agg3_k(const float* __restrict__ h3, const float* __restrict__ s3,
                                              const float* __restrict__ d3, const int* __restrict__ indptr,
                                              const int* __restrict__ srcs, const float* __restrict__ b3,
                                              float* __restrict__ out, int N) {
    int t = blockIdx.x * 256 + threadIdx.x;
    int n = t >> 2;
    if (n >= N) return;
    int sub = t & 3;
    float ad = d3[n];
    float m = MNEG, den = 0.f, a0 = 0.f, a1 = 0.f;
    int beg = indptr[n], end = indptr[n + 1];
    for (int k = beg + sub; k < end; k += 4) {
        int s = srcs[k];
        float e = s3[s] + ad;
        e = fmaxf(e, 0.2f * e);
        if (e > m + 4.f) {
            float mn = fmaxf(m, e);
            float sc = exp2f(m - mn);
            den *= sc; a0 *= sc; a1 *= sc;
            m = mn;
        }
        float p = exp2f(e - m);
        den += p;
        a0 += p * h3[(size_t)s * 2];
        a1 += p * h3[(size_t)s * 2 + 1];
    }
#pragma unroll
    for (int off = 1; off < 4; off <<= 1) {
        float m2 = __shfl_xor(m, off);
        float den2 = __shfl_xor(den, off);
        float a02 = __shfl_xor(a0, off);
        float a12 = __shfl_xor(a1, off);
        float mn = fmaxf(m, m2);
        float sc1 = exp2f(m - mn);
        float sc2 = exp2f(m2 - mn);
        den = den * sc1 + den2 * sc2;
        a0 = a0 * sc1 + a02 * sc2;
        a1 = a1 * sc1 + a12 * sc2;
        m = mn;
    }
    if (sub == 0) {
        float inv = 1.f / (den + 1e-16f);
        out[(size_t)n * 2]     = a0 * inv + b3[0];
        out[(size_t)n * 2 + 1] = a1 * inv + b3[1];
    }
}

// ---------------- launch ----------------

extern "C" void kernel_launch(void* const* d_in, const int* in_sizes, int n_in,
                              void* d_out, int out_size, void* d_ws, size_t ws_size,
                              hipStream_t stream) {
    const float* x   = (const float*)d_in[0];
    const int*   ei  = (const int*)d_in[1];
    const float* W1  = (const float*)d_in[2];
    const float* as1 = (const float*)d_in[3];
    const float* ad1 = (const float*)d_in[4];
    const float* b1  = (const float*)d_in[5];
    const float* W2  = (const float*)d_in[6];
    const float* as2 = (const float*)d_in[7];
    const float* ad2 = (const float*)d_in[8];
    const float* b2  = (const float*)d_in[9];
    const float* W3  = (const float*)d_in[10];
    const float* at_s3 = (const float*)d_in[11];
    const float* at_d3 = (const float*)d_in[12];
    const float* b3  = (const float*)d_in[13];

    int N = in_sizes[0] / NF;   // 50000
    int E = in_sizes[1] / 2;    // 800000
    const int* esrc = ei;
    const int* edst = ei + E;

    char* w = (char*)d_ws;
    _Float16* hbuf  = (_Float16*)w; w += (size_t)N * NF * 2;
    _Float16* xnext = (_Float16*)w; w += (size_t)N * NF * 2;
    float* aS    = (float*)w; w += (size_t)N * NHEADS * 4;
    float* aD    = (float*)w; w += (size_t)N * NHEADS * 4;
    float* h3    = (float*)w; w += (size_t)N * 2 * 4;
    float* s3    = (float*)w; w += (size_t)N * 4;
    float* d3    = (float*)w; w += (size_t)N * 4;
    int* deg     = (int*)w; w += (size_t)N * 4;
    int* indptr  = (int*)w; w += (size_t)(N + 1) * 4 + 60;
    int* cursor  = (int*)w; w += (size_t)N * 4;
    int* bsum    = (int*)w; w += 256 * 4;
    _Float16* WTh1 = (_Float16*)w; w += (size_t)256 * 256 * 2;
    _Float16* WTh2 = (_Float16*)w; w += (size_t)256 * 256 * 2;
    int* srcs    = (int*)w;

    int nb_n = (N + 255) / 256;       // 196
    int nb_e4 = (E + 1023) / 1024;    // 782 (deg_count blocks)
    int nb_f  = (E + 2047) / 2048;    // 391 (fill blocks, 512 thr x 4 edges)
    int nb_w = (N + 3) / 4;
    int nb_gm = (N + 127) / 128;      // 391
    int nb_a3 = (N * 4 + 255) / 256;

    // CSR build overlapped with weight prep / GEMM1
    hipMemsetAsync(deg, 0, (size_t)N * 4, stream);
    misc_k<<<nb_e4 + 512, 256, 0, stream>>>(edst, deg, E, nb_e4, W1, W2, WTh1, WTh2);
    scan1_k<<<nb_n, 256, 0, stream>>>(deg, indptr, bsum, N);
    scan3_k<<<nb_n, 256, 0, stream>>>(deg, indptr, bsum, cursor, srcs, N, nb_n);

    // layer 1 GEMM ∥ fill_edge
    gemm_mfma_k<1><<<nb_gm + nb_f, 512, 0, stream>>>(x, WTh1, as1, ad1, hbuf, aS, aD, N,
                                                     esrc, edst, cursor, srcs, E, nb_gm);
    agg_k<0><<<nb_w, 256, 0, stream>>>(hbuf, aS, aD, indptr, srcs, b1, xnext,
                                       nullptr, nullptr, nullptr, nullptr, nullptr, nullptr, N);
    // layer 2 (+ fused layer-3 matvec)
    gemm_mfma_k<0><<<nb_gm, 512, 0, stream>>>(xnext, WTh2, as2, ad2, hbuf, aS, aD, N,
                                              nullptr, nullptr, nullptr, nullptr, 0, nb_gm);
    agg_k<1><<<nb_w, 256, 0, stream>>>(hbuf, aS, aD, indptr, srcs, b2, nullptr,
                                       W3, at_s3, at_d3, h3, s3, d3, N);
    // layer 3 aggregation
    agg3_k<<<nb_a3, 256, 0, stream>>>(h3, s3, d3, indptr, srcs, b3, (float*)d_out, N);
}

// Round 12
// 270.007 us; speedup vs baseline: 1.0941x; 1.0211x over previous
//
#include <hip/hip_runtime.h>
#include <math.h>

#define NF 256
#define NHEADS 8
#define MNEG -1e30f

typedef _Float16 half8 __attribute__((ext_vector_type(8)));
typedef float f32x4 __attribute__((ext_vector_type(4)));

// ---------------- CSR phase A: deg_count (blocks [0,nbE)) ∥ prep_w (blocks [nbE,nbE+512)) ----------------

__global__ __launch_bounds__(256) void misc_k(const int* __restrict__ edst, int* __restrict__ deg, int E, int nbE,
                                              const float* __restrict__ W1, const float* __restrict__ W2,
                                              _Float16* __restrict__ O1, _Float16* __restrict__ O2) {
    int bid = blockIdx.x;
    if (bid < nbE) {
        int i = (bid * 256 + threadIdx.x) * 4;
        if (i + 4 <= E) {
            int4 d = *(const int4*)&edst[i];
            atomicAdd(&deg[d.x], 1);
            atomicAdd(&deg[d.y], 1);
            atomicAdd(&deg[d.z], 1);
            atomicAdd(&deg[d.w], 1);
        } else {
            for (int e = i; e < E; ++e) atomicAdd(&deg[edst[e]], 1);
        }
    } else {
        int tid = (bid - nbE) * 256 + threadIdx.x;   // 0..131071
        const float* W = (tid < 65536) ? W1 : W2;
        _Float16* O = (tid < 65536) ? O1 : O2;
        int t = tid & 65535;
        int k = t >> 8, c = t & 255;
        O[(size_t)c * 256 + k] = (_Float16)W[t];
    }
}

__global__ __launch_bounds__(256) void scan1_k(const int* __restrict__ deg, int* __restrict__ indptr,
                                               int* __restrict__ bsum, int n) {
    __shared__ int sh[256];
    int tid = threadIdx.x;
    int i = blockIdx.x * 256 + tid;
    int d = (i < n) ? deg[i] : 0;
    sh[tid] = d;
    __syncthreads();
#pragma unroll
    for (int off = 1; off < 256; off <<= 1) {
        int t = (tid >= off) ? sh[tid - off] : 0;
        __syncthreads();
        sh[tid] += t;
        __syncthreads();
    }
    if (i < n) indptr[i] = sh[tid] - d;
    if (tid == 255) bsum[blockIdx.x] = sh[255];
}

// scan of block sums (redundant per block) + finalize indptr + seed self-loop/cursor
__global__ __launch_bounds__(256) void scan3_k(const int* __restrict__ deg, int* __restrict__ indptr,
                                               const int* __restrict__ bsum, int* __restrict__ cursor,
                                               int* __restrict__ srcs, int n, int nb) {
    __shared__ int sh[256];
    int tid = threadIdx.x;
    int d = (tid < nb) ? bsum[tid] : 0;
    sh[tid] = d;
    __syncthreads();
#pragma unroll
    for (int off = 1; off < 256; off <<= 1) {
        int t = (tid >= off) ? sh[tid - off] : 0;
        __syncthreads();
        sh[tid] += t;
        __syncthreads();
    }
    int bid = blockIdx.x;
    int boff = sh[bid] - ((bid < nb) ? bsum[bid] : 0);
    int i = bid * 256 + tid;
    if (i < n) {
        int v = indptr[i] + boff + i;
        indptr[i] = v;
        srcs[v] = i;           // self loop first
        cursor[i] = v + 1;
        if (i == n - 1) indptr[n] = v + deg[i] + 1;
    }
}

// ---------------- MFMA f16 GEMM + fused alpha (double-buffered, BK=32) ∥ fill_edge ----------------
// Blocks [0,GB): GEMM, 512 thr = 8 waves (2m x 4n), tile 128x256.
// Blocks [GB,...): fill_edge, 4 edges/thread (runs concurrently; both finish before agg).

template <int AF32>
__global__ __launch_bounds__(512, 4) void gemm_mfma_k(const void* __restrict__ Av, const _Float16* __restrict__ WTh,
                                                      const float* __restrict__ att_s, const float* __restrict__ att_d,
                                                      _Float16* __restrict__ C, float* __restrict__ aS,
                                                      float* __restrict__ aD, int M,
                                                      const int* __restrict__ esrc, const int* __restrict__ edst,
                                                      int* __restrict__ cursor, int* __restrict__ srcs,
                                                      int E, int GB) {
    __shared__ __align__(16) _Float16 Asub[2][128][40];
    __shared__ __align__(16) _Float16 Wsub[2][256][40];
    if (blockIdx.x >= GB) {   // fill_edge part
        int i = ((blockIdx.x - GB) * 512 + threadIdx.x) * 4;
        if (i + 4 <= E) {
            int4 s = *(const int4*)&esrc[i];
            int4 d = *(const int4*)&edst[i];
            srcs[atomicAdd(&cursor[d.x], 1)] = s.x;
            srcs[atomicAdd(&cursor[d.y], 1)] = s.y;
            srcs[atomicAdd(&cursor[d.z], 1)] = s.z;
            srcs[atomicAdd(&cursor[d.w], 1)] = s.w;
        } else {
            for (int e = i; e < E; ++e) srcs[atomicAdd(&cursor[edst[e]], 1)] = esrc[e];
        }
        return;
    }
    int t = threadIdx.x;
    int wave = t >> 6, lane = t & 63;
    int wm = wave >> 2, wn = wave & 3;        // 2 x 4 wave grid
    int lr = lane & 15, lg = lane >> 4;
    int r0 = blockIdx.x * 128;
    const float* Af = (const float*)Av;
    const _Float16* Ah = (const _Float16*)Av;

    int arow = t >> 2, aoff = (t & 3) * 8;      // 8 halfs
    int wcol = t >> 1, woff = (t & 1) * 16;     // 16 halfs
    int ga_row = r0 + arow; ga_row = ga_row < M ? ga_row : M - 1;

    half8 aR, wR0, wR1;
    {
        if (AF32) {
            const float* p = Af + (size_t)ga_row * 256 + aoff;
            float4 x0 = *(const float4*)p;
            float4 x1 = *(const float4*)(p + 4);
            aR[0] = (_Float16)x0.x; aR[1] = (_Float16)x0.y; aR[2] = (_Float16)x0.z; aR[3] = (_Float16)x0.w;
            aR[4] = (_Float16)x1.x; aR[5] = (_Float16)x1.y; aR[6] = (_Float16)x1.z; aR[7] = (_Float16)x1.w;
        } else {
            aR = *(const half8*)(Ah + (size_t)ga_row * 256 + aoff);
        }
        const _Float16* p = WTh + (size_t)wcol * 256 + woff;
        wR0 = *(const half8*)p;
        wR1 = *(const half8*)(p + 8);
    }
    *(half8*)&Asub[0][arow][aoff] = aR;
    *(half8*)&Wsub[0][wcol][woff] = wR0;
    *(half8*)&Wsub[0][wcol][woff + 8] = wR1;
    __syncthreads();

    f32x4 acc[4][4];
#pragma unroll
    for (int mr = 0; mr < 4; ++mr)
#pragma unroll
        for (int nr = 0; nr < 4; ++nr) acc[mr][nr] = (f32x4){0.f, 0.f, 0.f, 0.f};

#pragma unroll
    for (int ks = 0; ks < 8; ++ks) {
        int cur = ks & 1;
        if (ks < 7) {
            int k0 = (ks + 1) * 32;
            if (AF32) {
                const float* p = Af + (size_t)ga_row * 256 + k0 + aoff;
                float4 x0 = *(const float4*)p;
                float4 x1 = *(const float4*)(p + 4);
                aR[0] = (_Float16)x0.x; aR[1] = (_Float16)x0.y; aR[2] = (_Float16)x0.z; aR[3] = (_Float16)x0.w;
                aR[4] = (_Float16)x1.x; aR[5] = (_Float16)x1.y; aR[6] = (_Float16)x1.z; aR[7] = (_Float16)x1.w;
            } else {
                aR = *(const half8*)(Ah + (size_t)ga_row * 256 + k0 + aoff);
            }
            const _Float16* p = WTh + (size_t)wcol * 256 + k0 + woff;
            wR0 = *(const half8*)p;
            wR1 = *(const half8*)(p + 8);
        }
        {
            half8 a[4], b[4];
#pragma unroll
            for (int mr = 0; mr < 4; ++mr)
                a[mr] = *(const half8*)&Asub[cur][wm * 64 + mr * 16 + lr][lg * 8];
#pragma unroll
            for (int nr = 0; nr < 4; ++nr)
                b[nr] = *(const half8*)&Wsub[cur][wn * 64 + nr * 16 + lr][lg * 8];
#pragma unroll
            for (int mr = 0; mr < 4; ++mr)
#pragma unroll
                for (int nr = 0; nr < 4; ++nr)
                    acc[mr][nr] = __builtin_amdgcn_mfma_f32_16x16x32_f16(a[mr], b[nr], acc[mr][nr], 0, 0, 0);
        }
        if (ks < 7) {
            __syncthreads();
            *(half8*)&Asub[cur ^ 1][arow][aoff] = aR;
            *(half8*)&Wsub[cur ^ 1][wcol][woff] = wR0;
            *(half8*)&Wsub[cur ^ 1][wcol][woff + 8] = wR1;
            __syncthreads();
        }
    }

    int c0 = wn * 64;
    int h0 = wn * 2, h1 = wn * 2 + 1;
    float as_c0 = att_s[h0 * 32 + lr],      as_c1 = att_s[h0 * 32 + 16 + lr];
    float as_c2 = att_s[h1 * 32 + lr],      as_c3 = att_s[h1 * 32 + 16 + lr];
    float ad_c0 = att_d[h0 * 32 + lr],      ad_c1 = att_d[h0 * 32 + 16 + lr];
    float ad_c2 = att_d[h1 * 32 + lr],      ad_c3 = att_d[h1 * 32 + 16 + lr];

#pragma unroll
    for (int mr = 0; mr < 4; ++mr) {
        int rbase = r0 + wm * 64 + mr * 16 + lg * 4;
#pragma unroll
        for (int j = 0; j < 4; ++j) {
            int row = rbase + j;
            float ps0 = acc[mr][0][j] * as_c0 + acc[mr][1][j] * as_c1;
            float ps1 = acc[mr][2][j] * as_c2 + acc[mr][3][j] * as_c3;
            float pd0 = acc[mr][0][j] * ad_c0 + acc[mr][1][j] * ad_c1;
            float pd1 = acc[mr][2][j] * ad_c2 + acc[mr][3][j] * ad_c3;
#pragma unroll
            for (int o = 1; o < 16; o <<= 1) {
                ps0 += __shfl_xor(ps0, o);
                ps1 += __shfl_xor(ps1, o);
                pd0 += __shfl_xor(pd0, o);
                pd1 += __shfl_xor(pd1, o);
            }
            if (row < M) {
#pragma unroll
                for (int nr = 0; nr < 4; ++nr)
                    C[(size_t)row * 256 + c0 + nr * 16 + lr] = (_Float16)acc[mr][nr][j];
                if (lr == 0) {
                    aS[(size_t)row * NHEADS + h0] = ps0;
                    aS[(size_t)row * NHEADS + h1] = ps1;
                    aD[(size_t)row * NHEADS + h0] = pd0;
                    aD[(size_t)row * NHEADS + h1] = pd1;
                }
            }
        }
    }
}

// ---------------- aggregation: wave per dst, 4 pairs (8 edges) per iter (r8 config) ----------------
// MODE 0: write fp16 row (layer1). MODE 1: fuse layer-3 matvec -> h3/s3/d3 (layer2).

template <int MODE>
__global__ __launch_bounds__(256) void agg_k(const _Float16* __restrict__ h, const float* __restrict__ aS,
                                             const float* __restrict__ aD, const int* __restrict__ indptr,
                                             const int* __restrict__ srcs, const float* __restrict__ bias,
                                             _Float16* __restrict__ out,
                                             const float* __restrict__ W3, const float* __restrict__ as3,
                                             const float* __restrict__ ad3, float* __restrict__ h3,
                                             float* __restrict__ s3, float* __restrict__ d3, int N) {
    int wid = blockIdx.x * 4 + (threadIdx.x >> 6);
    if (wid >= N) return;
    int lane = threadIdx.x & 63;
    int hf = lane >> 5;          // which edge of a pair
    int cl = lane & 31;          // channel-lane: 8 ch at cl*8
    int hh = cl >> 2;            // head
    float ad = aD[(size_t)wid * NHEADS + hh];
    int beg = indptr[wid], end = indptr[wid + 1];
    const half8* h8p = (const half8*)h;
    float m = MNEG, den = 0.f;
    float f0 = 0, f1 = 0, f2 = 0, f3 = 0, f4 = 0, f5 = 0, f6 = 0, f7 = 0;
    int k = beg;
    int sp[4];
    if (k + 8 <= end) {
#pragma unroll
        for (int j = 0; j < 4; ++j) sp[j] = srcs[k + 2 * j + hf];
    }
    for (; k + 8 <= end; k += 8) {
        int s[4]; float as[4]; half8 v[4]; float e[4];
#pragma unroll
        for (int j = 0; j < 4; ++j) s[j] = sp[j];
        if (k + 16 <= end) {
#pragma unroll
            for (int j = 0; j < 4; ++j) sp[j] = srcs[k + 8 + 2 * j + hf];
        }
#pragma unroll
        for (int j = 0; j < 4; ++j) as[j] = aS[(size_t)s[j] * NHEADS + hh];
#pragma unroll
        for (int j = 0; j < 4; ++j) v[j] = h8p[(size_t)s[j] * 32 + cl];
#pragma unroll
        for (int j = 0; j < 4; ++j) { e[j] = as[j] + ad; e[j] = fmaxf(e[j], 0.2f * e[j]); }
        float em = fmaxf(fmaxf(e[0], e[1]), fmaxf(e[2], e[3]));
        if (__any(em > m + 4.f)) {
            float mn = fmaxf(m, em);
            float sc = __expf(m - mn);
            den *= sc; f0 *= sc; f1 *= sc; f2 *= sc; f3 *= sc; f4 *= sc; f5 *= sc; f6 *= sc; f7 *= sc;
            m = mn;
        }
        half8 hacc = (half8)(_Float16)0.f;
#pragma unroll
        for (int j = 0; j < 4; ++j) {
            float p = __expf(e[j] - m);
            den += p;
            _Float16 ph = (_Float16)p;
            half8 pb = {ph, ph, ph, ph, ph, ph, ph, ph};
            hacc += v[j] * pb;
        }
        f0 += (float)hacc[0]; f1 += (float)hacc[1]; f2 += (float)hacc[2]; f3 += (float)hacc[3];
        f4 += (float)hacc[4]; f5 += (float)hacc[5]; f6 += (float)hacc[6]; f7 += (float)hacc[7];
    }
    for (; k + 2 <= end; k += 2) {
        int s = srcs[k + hf];
        float as = aS[(size_t)s * NHEADS + hh];
        half8 v = h8p[(size_t)s * 32 + cl];
        float e = as + ad; e = fmaxf(e, 0.2f * e);
        if (__any(e > m + 4.f)) {
            float mn = fmaxf(m, e);
            float sc = __expf(m - mn);
            den *= sc; f0 *= sc; f1 *= sc; f2 *= sc; f3 *= sc; f4 *= sc; f5 *= sc; f6 *= sc; f7 *= sc;
            m = mn;
        }
        float p = __expf(e - m);
        den += p;
        f0 += p * (float)v[0]; f1 += p * (float)v[1]; f2 += p * (float)v[2]; f3 += p * (float)v[3];
        f4 += p * (float)v[4]; f5 += p * (float)v[5]; f6 += p * (float)v[6]; f7 += p * (float)v[7];
    }
    if (k < end) {
        int s = srcs[k];
        float e = aS[(size_t)s * NHEADS + hh] + ad;
        e = fmaxf(e, 0.2f * e);
        half8 v = h8p[(size_t)s * 32 + cl];
        float eg = (hf == 0) ? e : MNEG;
        if (__any(eg > m + 4.f)) {
            float mn = fmaxf(m, eg);
            float sc = __expf(m - mn);
            den *= sc; f0 *= sc; f1 *= sc; f2 *= sc; f3 *= sc; f4 *= sc; f5 *= sc; f6 *= sc; f7 *= sc;
            m = mn;
        }
        float p = (hf == 0) ? __expf(e - m) : 0.f;
        den += p;
        f0 += p * (float)v[0]; f1 += p * (float)v[1]; f2 += p * (float)v[2]; f3 += p * (float)v[3];
        f4 += p * (float)v[4]; f5 += p * (float)v[5]; f6 += p * (float)v[6]; f7 += p * (float)v[7];
    }
    // merge the two half-states (lane l <-> l+32)
    {
        float m2 = __shfl_xor(m, 32);
        float den2 = __shfl_xor(den, 32);
        float mn = fmaxf(m, m2);
        float sc1 = __expf(m - mn), sc2 = __expf(m2 - mn);
        den = den * sc1 + den2 * sc2;
        f0 = f0 * sc1 + __shfl_xor(f0, 32) * sc2;
        f1 = f1 * sc1 + __shfl_xor(f1, 32) * sc2;
        f2 = f2 * sc1 + __shfl_xor(f2, 32) * sc2;
        f3 = f3 * sc1 + __shfl_xor(f3, 32) * sc2;
        f4 = f4 * sc1 + __shfl_xor(f4, 32) * sc2;
        f5 = f5 * sc1 + __shfl_xor(f5, 32) * sc2;
        f6 = f6 * sc1 + __shfl_xor(f6, 32) * sc2;
        f7 = f7 * sc1 + __shfl_xor(f7, 32) * sc2;
    }
    float inv = 1.f / (den + 1e-16f);
    float4 bv0 = *(const float4*)&bias[cl * 8];
    float4 bv1 = *(const float4*)&bias[cl * 8 + 4];
    float o[8];
    o[0] = f0 * inv + bv0.x; o[1] = f1 * inv + bv0.y; o[2] = f2 * inv + bv0.z; o[3] = f3 * inv + bv0.w;
    o[4] = f4 * inv + bv1.x; o[5] = f5 * inv + bv1.y; o[6] = f6 * inv + bv1.z; o[7] = f7 * inv + bv1.w;
#pragma unroll
    for (int c = 0; c < 8; ++c) o[c] = (o[c] > 0.f) ? o[c] : expm1f(o[c]);  // ELU

    if (MODE == 0) {
        if (hf == 0) {
            half8 ov;
#pragma unroll
            for (int c = 0; c < 8; ++c) ov[c] = (_Float16)o[c];
            ((half8*)out)[(size_t)wid * 32 + cl] = ov;
        }
    } else {
        const float4* W34 = (const float4*)W3;
        float p0 = 0.f, p1 = 0.f;
#pragma unroll
        for (int q = 0; q < 4; ++q) {
            float4 w = W34[cl * 4 + q];
            p0 += o[2 * q] * w.x + o[2 * q + 1] * w.z;
            p1 += o[2 * q] * w.y + o[2 * q + 1] * w.w;
        }
#pragma unroll
        for (int off = 1; off < 32; off <<= 1) {
            p0 += __shfl_xor(p0, off);
            p1 += __shfl_xor(p1, off);
        }
        if (lane == 0) {
            h3[(size_t)wid * 2] = p0;
            h3[(size_t)wid * 2 + 1] = p1;
            s3[wid] = p0 * as3[0] + p1 * as3[1];
            d3[wid] = p0 * ad3[0] + p1 * ad3[1];
        }
    }
}

// ---------------- layer 3 aggregation: 4 lanes per dst node + shuffle merge ----------------

__global__ __launch_bounds__(256) void agg3_k(const float* __restrict__ h3, const float* __restrict__ s3,
                                              const float* __restrict__ d3, const int* __restrict__ indptr,
                                              const int* __restrict__ srcs, const float* __restrict__ b3,
                                              float* __restrict__ out, int N) {
    int t = blockIdx.x * 256 + threadIdx.x;
    int n = t >> 2;
    if (n >= N) return;
    int sub = t & 3;
    float ad = d3[n];
    float m = MNEG, den = 0.f, a0 = 0.f, a1 = 0.f;
    int beg = indptr[n], end = indptr[n + 1];
    for (int k = beg + sub; k < end; k += 4) {
        int s = srcs[k];
        float e = s3[s] + ad;
        e = fmaxf(e, 0.2f * e);
        if (e > m + 4.f) {
            float mn = fmaxf(m, e);
            float sc = __expf(m - mn);
            den *= sc; a0 *= sc; a1 *= sc;
            m = mn;
        }
        float p = __expf(e - m);
        den += p;
        a0 += p * h3[(size_t)s * 2];
        a1 += p * h3[(size_t)s * 2 + 1];
    }
#pragma unroll
    for (int off = 1; off < 4; off <<= 1) {
        float m2 = __shfl_xor(m, off);
        float den2 = __shfl_xor(den, off);
        float a02 = __shfl_xor(a0, off);
        float a12 = __shfl_xor(a1, off);
        float mn = fmaxf(m, m2);
        float sc1 = __expf(m - mn);
        float sc2 = __expf(m2 - mn);
        den = den * sc1 + den2 * sc2;
        a0 = a0 * sc1 + a02 * sc2;
        a1 = a1 * sc1 + a12 * sc2;
        m = mn;
    }
    if (sub == 0) {
        float inv = 1.f / (den + 1e-16f);
        out[(size_t)n * 2]     = a0 * inv + b3[0];
        out[(size_t)n * 2 + 1] = a1 * inv + b3[1];
    }
}

// ---------------- launch ----------------

extern "C" void kernel_launch(void* const* d_in, const int* in_sizes, int n_in,
                              void* d_out, int out_size, void* d_ws, size_t ws_size,
                              hipStream_t stream) {
    const float* x   = (const float*)d_in[0];
    const int*   ei  = (const int*)d_in[1];
    const float* W1  = (const float*)d_in[2];
    const float* as1 = (const float*)d_in[3];
    const float* ad1 = (const float*)d_in[4];
    const float* b1  = (const float*)d_in[5];
    const float* W2  = (const float*)d_in[6];
    const float* as2 = (const float*)d_in[7];
    const float* ad2 = (const float*)d_in[8];
    const float* b2  = (const float*)d_in[9];
    const float* W3  = (const float*)d_in[10];
    const float* at_s3 = (const float*)d_in[11];
    const float* at_d3 = (const float*)d_in[12];
    const float* b3  = (const float*)d_in[13];

    int N = in_sizes[0] / NF;   // 50000
    int E = in_sizes[1] / 2;    // 800000
    const int* esrc = ei;
    const int* edst = ei + E;

    char* w = (char*)d_ws;
    _Float16* hbuf  = (_Float16*)w; w += (size_t)N * NF * 2;
    _Float16* xnext = (_Float16*)w; w += (size_t)N * NF * 2;
    float* aS    = (float*)w; w += (size_t)N * NHEADS * 4;
    float* aD    = (float*)w; w += (size_t)N * NHEADS * 4;
    float* h3    = (float*)w; w += (size_t)N * 2 * 4;
    float* s3    = (float*)w; w += (size_t)N * 4;
    float* d3    = (float*)w; w += (size_t)N * 4;
    int* deg     = (int*)w; w += (size_t)N * 4;
    int* indptr  = (int*)w; w += (size_t)(N + 1) * 4 + 60;
    int* cursor  = (int*)w; w += (size_t)N * 4;
    int* bsum    = (int*)w; w += 256 * 4;
    _Float16* WTh1 = (_Float16*)w; w += (size_t)256 * 256 * 2;
    _Float16* WTh2 = (_Float16*)w; w += (size_t)256 * 256 * 2;
    int* srcs    = (int*)w;

    int nb_n = (N + 255) / 256;       // 196
    int nb_e4 = (E + 1023) / 1024;    // 782 (deg_count blocks)
    int nb_f  = (E + 2047) / 2048;    // 391 (fill blocks, 512 thr x 4 edges)
    int nb_w = (N + 3) / 4;
    int nb_gm = (N + 127) / 128;      // 391
    int nb_a3 = (N * 4 + 255) / 256;

    // CSR build overlapped with weight prep / GEMM1
    hipMemsetAsync(deg, 0, (size_t)N * 4, stream);
    misc_k<<<nb_e4 + 512, 256, 0, stream>>>(edst, deg, E, nb_e4, W1, W2, WTh1, WTh2);
    scan1_k<<<nb_n, 256, 0, stream>>>(deg, indptr, bsum, N);
    scan3_k<<<nb_n, 256, 0, stream>>>(deg, indptr, bsum, cursor, srcs, N, nb_n);

    // layer 1 GEMM ∥ fill_edge
    gemm_mfma_k<1><<<nb_gm + nb_f, 512, 0, stream>>>(x, WTh1, as1, ad1, hbuf, aS, aD, N,
                                                     esrc, edst, cursor, srcs, E, nb_gm);
    agg_k<0><<<nb_w, 256, 0, stream>>>(hbuf, aS, aD, indptr, srcs, b1, xnext,
                                       nullptr, nullptr, nullptr, nullptr, nullptr, nullptr, N);
    // layer 2 (+ fused layer-3 matvec)
    gemm_mfma_k<0><<<nb_gm, 512, 0, stream>>>(xnext, WTh2, as2, ad2, hbuf, aS, aD, N,
                                              nullptr, nullptr, nullptr, nullptr, 0, nb_gm);
    agg_k<1><<<nb_w, 256, 0, stream>>>(hbuf, aS, aD, indptr, srcs, b2, nullptr,
                                       W3, at_s3, at_d3, h3, s3, d3, N);
    // layer 3 aggregation
    agg3_k<<<nb_a3, 256, 0, stream>>>(h3, s3, d3, indptr, srcs, b3, (float*)d_out, N);
}